// Round 4
// baseline (138.027 us; speedup 1.0000x reference)
//
#include <hip/hip_runtime.h>
#include <stdint.h>

// pooled[b,p] = sum_{n in seg b} max_e ( proxy[p,e,:] . x[n,:] );  out = L2-normalized rows.
// P=128, E=32, D=64, B=1024 segments. Ragged handled via zeroed-B masking.
//
// R3: coalesced fragment-major A (kept from R2) + occupancy fix:
//  - wave = (wn, wp): 2 n-tiles x 64 p -> bfrag 32 + acc 32 + zc 16 + A-dbuf 32
//    ~= 126 VGPR -> __launch_bounds__(256,4) -> 4 waves/SIMD, all blocks resident.
//    (R2's 4-tile wave needed ~196 regs -> 2 waves/SIMD -> MfmaUtil stuck at 38%.)
//  - invalid columns masked by ZEROING B-frags at load (max_e(0)=0): no epilogue masks.
//  - zero-C trick, max3-tree e-reduction, LDS-deferred col-reduction, fused normalize.

typedef short short8 __attribute__((ext_vector_type(8)));
typedef __bf16 bf16x8 __attribute__((ext_vector_type(8)));
typedef float floatx16 __attribute__((ext_vector_type(16)));

#define NELEM 32
#define DIM   64
#define NSEG  1024
#define LROW  68   /* buf row stride (floats): 64 cols + 4 pad; 272B rows, 16B-aligned */

__device__ __forceinline__ unsigned short f32_to_bf16_rne(float f) {
  union { float f; unsigned int u; } v; v.f = f;
  unsigned int r = v.u + 0x7fffu + ((v.u >> 16) & 1u);
  return (unsigned short)(r >> 16);
}

// Block 0: exclusive scan of segment lengths -> offs[0..NSEG].
// Blocks 1..128: proxy fp32 -> fragment-major bf16 pb2:
//   frag(p,kk) = contiguous 1KB at (p*4+kk)*512 shorts; lane slot = +lane*8.
__global__ void sc_prep(const float* __restrict__ proxy,
                        const int* __restrict__ index,
                        short* __restrict__ pb2,
                        int* __restrict__ offs) {
  const int bx = blockIdx.x, t = threadIdx.x;
  if (bx == 0) {
    __shared__ int lsum[256];
    const int base = t * 4;
    const int i0 = index[base + 0], i1 = index[base + 1];
    const int i2 = index[base + 2], i3 = index[base + 3];
    const int s = i0 + i1 + i2 + i3;
    lsum[t] = s;
    __syncthreads();
    for (int off = 1; off < 256; off <<= 1) {
      int v = (t >= off) ? lsum[t - off] : 0;
      __syncthreads();
      lsum[t] += v;
      __syncthreads();
    }
    const int ex = lsum[t] - s;
    offs[base + 0] = ex;
    offs[base + 1] = ex + i0;
    offs[base + 2] = ex + i0 + i1;
    offs[base + 3] = ex + i0 + i1 + i2;
    if (t == 255) offs[NSEG] = ex + s;
  } else {
    const int w = t >> 6, lane = t & 63;
    const int task = (bx - 1) * 4 + w;   // 0..511 = (p, kk)
    const int p = task >> 2, kk = task & 3;
    const int l31 = lane & 31, h = lane >> 5;
    const float* src = proxy + (size_t)p * (NELEM * DIM) + l31 * DIM + kk * 16 + h * 8;
    float4 f0 = *(const float4*)(src);
    float4 f1 = *(const float4*)(src + 4);
    short8 fr;
    fr[0] = (short)f32_to_bf16_rne(f0.x);
    fr[1] = (short)f32_to_bf16_rne(f0.y);
    fr[2] = (short)f32_to_bf16_rne(f0.z);
    fr[3] = (short)f32_to_bf16_rne(f0.w);
    fr[4] = (short)f32_to_bf16_rne(f1.x);
    fr[5] = (short)f32_to_bf16_rne(f1.y);
    fr[6] = (short)f32_to_bf16_rne(f1.z);
    fr[7] = (short)f32_to_bf16_rne(f1.w);
    *(short8*)(pb2 + ((size_t)task * 64 + lane) * 8) = fr;  // coalesced 1KB/wave
  }
}

__device__ __forceinline__ float max16(const floatx16& a) {
  float r0 = fmaxf(fmaxf(a[0], a[1]), a[2]);
  float r1 = fmaxf(fmaxf(a[3], a[4]), a[5]);
  float r2 = fmaxf(fmaxf(a[6], a[7]), a[8]);
  float r3 = fmaxf(fmaxf(a[9], a[10]), a[11]);
  float r4 = fmaxf(fmaxf(a[12], a[13]), a[14]);
  float r5 = fmaxf(fmaxf(r0, r1), r2);
  float r6 = fmaxf(fmaxf(r3, r4), a[15]);
  return fmaxf(r5, r6);
}

__global__ __launch_bounds__(256, 4) void sc_main(
    const float* __restrict__ x,
    const short* __restrict__ pb2,
    const int* __restrict__ offs,
    float* __restrict__ out,
    int nrows) {
  __shared__ float buf[128 * LROW];  // [p][wn*32 + col]
  __shared__ float red[4];

  const int b = blockIdx.x;
  const int tid = threadIdx.x;
  const int lane = tid & 63;
  const int w = tid >> 6;
  const int wn = w & 1;    // tile-pair: tiles wn*2 + {0,1} of each pass
  const int wp = w >> 1;   // p-half: p in [wp*64, wp*64+64)
  const int l31 = lane & 31;
  const int h = lane >> 5;

  const int start = offs[b];
  const int end = offs[b + 1];
  const int len = end - start;
  const int first = start >> 5;
  const int ntiles = (len > 0) ? (((end + 31) >> 5) - first) : 0;
  const int npass = (ntiles + 3) >> 2;

  if (ntiles == 0) {
    for (int j = tid; j < 128 * LROW; j += 256) buf[j] = 0.f;
  }

  floatx16 zc;  // permanently-zero C operand (no per-p acc init)
#pragma unroll
  for (int r = 0; r < 16; ++r) zc[r] = 0.f;

  // frag(p,kk) at pb2 + (p*4+kk)*512 + lane*8 shorts; p = wp*64 + i
  const short* abase = pb2 + (size_t)(wp * 64) * 2048 + lane * 8;

  for (int pass = 0; pass < npass; ++pass) {
    // B-frags: this wave's 2 tiles, fp32 -> bf16 in-reg. Invalid columns are
    // ZEROED (max_e(0) = 0 contributes nothing to the segment sum).
    short8 bfrag[2][4];
#pragma unroll
    for (int t4 = 0; t4 < 2; ++t4) {
      const int tile = first + pass * 4 + wn * 2 + t4;
      const int n = tile * 32 + l31;
      const bool valid = (n >= start) && (n < end) && (n < nrows);
      const float* xr = x + (size_t)(valid ? n : 0) * DIM + h * 8;
#pragma unroll
      for (int kk = 0; kk < 4; ++kk) {
        float4 f0 = make_float4(0.f, 0.f, 0.f, 0.f), f1 = f0;
        if (valid) {
          f0 = *(const float4*)(xr + kk * 16);
          f1 = *(const float4*)(xr + kk * 16 + 4);
        }
        short8 fr;
        fr[0] = (short)f32_to_bf16_rne(f0.x);
        fr[1] = (short)f32_to_bf16_rne(f0.y);
        fr[2] = (short)f32_to_bf16_rne(f0.z);
        fr[3] = (short)f32_to_bf16_rne(f0.w);
        fr[4] = (short)f32_to_bf16_rne(f1.x);
        fr[5] = (short)f32_to_bf16_rne(f1.y);
        fr[6] = (short)f32_to_bf16_rne(f1.z);
        fr[7] = (short)f32_to_bf16_rne(f1.w);
        bfrag[t4][kk] = fr;
      }
    }

    auto process = [&](int i, short8 (&cur)[4], short8 (&nxt)[4], bool pf) {
      if (pf) {  // double-buffered coalesced A prefetch (next p)
        const short* ap = abase + (size_t)(i + 1) * 2048;
#pragma unroll
        for (int kk = 0; kk < 4; ++kk)
          nxt[kk] = *(const short8*)(ap + kk * 512);
      }
      floatx16 a0, a1;  // 2 independent MFMA chains
#pragma unroll
      for (int kk = 0; kk < 4; ++kk) {
        bf16x8 a = __builtin_bit_cast(bf16x8, cur[kk]);
        bf16x8 b0 = __builtin_bit_cast(bf16x8, bfrag[0][kk]);
        bf16x8 b1 = __builtin_bit_cast(bf16x8, bfrag[1][kk]);
        if (kk == 0) {
          a0 = __builtin_amdgcn_mfma_f32_32x32x16_bf16(a, b0, zc, 0, 0, 0);
          a1 = __builtin_amdgcn_mfma_f32_32x32x16_bf16(a, b1, zc, 0, 0, 0);
        } else {
          a0 = __builtin_amdgcn_mfma_f32_32x32x16_bf16(a, b0, a0, 0, 0, 0);
          a1 = __builtin_amdgcn_mfma_f32_32x32x16_bf16(a, b1, a1, 0, 0, 0);
        }
      }
      // max over e: 16 in-lane rows + complementary 16 from lane^32
      float m0 = max16(a0), m1 = max16(a1);
      m0 = fmaxf(m0, __shfl_xor(m0, 32, 64));
      m1 = fmaxf(m1, __shfl_xor(m1, 32, 64));
      const float s = m0 + m1;  // partial sum over this wave's 2 tiles, col l31
      if (h == 0) {             // halves identical after xor-32; one writes
        const int idx = (wp * 64 + i) * LROW + wn * 32 + l31;  // conflict-free
        float prev = (pass == 0) ? 0.f : buf[idx];
        buf[idx] = prev + s;
      }
    };

    short8 afA[4], afB[4];
#pragma unroll
    for (int kk = 0; kk < 4; ++kk)
      afA[kk] = *(const short8*)(abase + kk * 512);
    for (int i = 0; i < 64; i += 2) {  // unroll-2: compile-time dbuf index
      process(i, afA, afB, true);
      process(i + 1, afB, afA, i < 62);
    }
  }
  __syncthreads();

  // Batched 64-col reduction + fused L2-normalize. 2 threads per p.
  const int p2 = tid >> 1, part = tid & 1;
  const float* bp = buf + p2 * LROW + part * 32;
  float4 v0 = *(const float4*)(bp + 0);
  float4 v1 = *(const float4*)(bp + 4);
  float4 v2 = *(const float4*)(bp + 8);
  float4 v3 = *(const float4*)(bp + 12);
  float4 v4 = *(const float4*)(bp + 16);
  float4 v5 = *(const float4*)(bp + 20);
  float4 v6 = *(const float4*)(bp + 24);
  float4 v7 = *(const float4*)(bp + 28);
  float sh = ((v0.x + v0.y) + (v0.z + v0.w)) + ((v1.x + v1.y) + (v1.z + v1.w)) +
             ((v2.x + v2.y) + (v2.z + v2.w)) + ((v3.x + v3.y) + (v3.z + v3.w)) +
             ((v4.x + v4.y) + (v4.z + v4.w)) + ((v5.x + v5.y) + (v5.z + v5.w)) +
             ((v6.x + v6.y) + (v6.z + v6.w)) + ((v7.x + v7.y) + (v7.z + v7.w));
  const float s64 = sh + __shfl_xor(sh, 1, 64);  // pooled[b][p2]

  float sq = part ? 0.f : s64 * s64;
#pragma unroll
  for (int off = 1; off <= 32; off <<= 1) sq += __shfl_xor(sq, off, 64);
  if (lane == 0) red[w] = sq;
  __syncthreads();
  const float ss = (red[0] + red[1]) + (red[2] + red[3]);
  const float inv = 1.f / fmaxf(sqrtf(ss), 1e-12f);
  if (part == 0) out[(b << 7) + p2] = s64 * inv;
}

extern "C" void kernel_launch(void* const* d_in, const int* in_sizes, int n_in,
                              void* d_out, int out_size, void* d_ws, size_t ws_size,
                              hipStream_t stream) {
  (void)n_in; (void)out_size; (void)ws_size;
  const float* x = (const float*)d_in[0];      // [N, 64] fp32
  const float* proxy = (const float*)d_in[1];  // [128, 32, 64] fp32
  const int* index = (const int*)d_in[2];      // [1024] int32
  float* out = (float*)d_out;                  // [1024, 128] fp32
  const int nrows = in_sizes[0] / DIM;

  int* offs = (int*)d_ws;                      // (NSEG+1) ints
  short* pb2 = (short*)((char*)d_ws + 8192);   // 512 KB fragment-major bf16 proxy

  sc_prep<<<129, 256, 0, stream>>>(proxy, index, pb2, offs);
  sc_main<<<NSEG, 256, 0, stream>>>(x, pb2, offs, out, nrows);
}